// Round 11
// baseline (179.330 us; speedup 1.0000x reference)
//
#include <hip/hip_runtime.h>
#include <hip/hip_bf16.h>
#include <cstdint>

typedef __attribute__((ext_vector_type(8))) __bf16 bf16x8;
typedef __attribute__((ext_vector_type(4))) float f32x4;

typedef __attribute__((address_space(1))) const void g_void;
typedef __attribute__((address_space(3))) void l_void;

__device__ __forceinline__ void gload_lds16(const void* g, void* l) {
  __builtin_amdgcn_global_load_lds((g_void*)(uintptr_t)g,
                                   (l_void*)(uint32_t)(uintptr_t)l, 16, 0, 0);
}

__device__ __forceinline__ ushort f2bf(float f) {
  union { float f; uint32_t u; } v; v.f = f;
  uint32_t r = v.u + 0x7fffu + ((v.u >> 16) & 1u);
  return (ushort)(r >> 16);
}

struct WDesc {
  const float* W[7];
  int nvec[7];
  int vcum[8];
};

// ---------- R10 prep: 2 fused kernels (verified −5.6 us vs split) ----------
__global__ void absmean_concat(WDesc wd, float* __restrict__ partials,
                               const float* __restrict__ z,
                               const float* __restrict__ att,
                               ushort* __restrict__ cat) {
  const int b = blockIdx.x;
  const int t = threadIdx.x;
  if (b < 448) {
    __shared__ float red[256];
    const int layer = b >> 6, blk = b & 63;
    const float4* W = (const float4*)wd.W[layer];
    const int nv = wd.nvec[layer];
    float s = 0.f;
    for (int i = blk * 256 + t; i < nv; i += 64 * 256) {
      float4 w = W[i];
      s += fabsf(w.x) + fabsf(w.y) + fabsf(w.z) + fabsf(w.w);
    }
    red[t] = s;
    __syncthreads();
    for (int o = 128; o > 0; o >>= 1) {
      if (t < o) red[t] += red[t + o];
      __syncthreads();
    }
    if (t == 0) partials[layer * 64 + blk] = red[0];
  } else {
    const int bc = b - 448;
    const int row = bc >> 1;
    const int h = bc & 1;
    const float* src = (h ? att : z) + (size_t)row * 1024 + t * 4;
    float4 a = *(const float4*)src;
    ushort4 o;
    o.x = f2bf(a.x); o.y = f2bf(a.y); o.z = f2bf(a.z); o.w = f2bf(a.w);
    *(ushort4*)(cat + (size_t)row * 2048 + h * 1024 + t * 4) = o;
  }
}

__global__ void quant_final(WDesc wd, const float* __restrict__ partials,
                            ushort* __restrict__ qw) {
  __shared__ float igs;
  const int t = threadIdx.x;
  const int v = blockIdx.x * 256 + t;
  const int v0 = blockIdx.x * 256;
  int layer = 0;
#pragma unroll
  for (int i = 1; i < 7; ++i) layer += (v0 >= wd.vcum[i]);
  if (t < 64) {
    float x = partials[layer * 64 + t];
    for (int o = 32; o > 0; o >>= 1) x += __shfl_down(x, o, 64);
    if (t == 0) {
      float mean = x / (float)(wd.nvec[layer] * 4);
      igs = 1.0f / (mean + 1e-8f);
    }
  }
  __syncthreads();
  if (v >= wd.vcum[7]) return;
  const float g = igs;
  const int lv = v - wd.vcum[layer];
  float4 w = ((const float4*)wd.W[layer])[lv];
  ushort4 o;
  o.x = f2bf(fmaxf(-1.f, fminf(1.f, rintf(w.x * g))));
  o.y = f2bf(fmaxf(-1.f, fminf(1.f, rintf(w.y * g))));
  o.z = f2bf(fmaxf(-1.f, fminf(1.f, rintf(w.z * g))));
  o.w = f2bf(fmaxf(-1.f, fminf(1.f, rintf(w.w * g))));
  ((ushort4*)qw)[v] = o;
}

// ---------- fast GELU (tanh form, branch-free) ----------
__device__ __forceinline__ float gelu_fast(float x) {
  float x2 = x * x;
  float u = x * fmaf(x2, 0.0356774081f, 0.7978845608f);
  float e = exp2f(u * 2.8853900818f);
  float r = __builtin_amdgcn_rcpf(e + 1.0f);
  return x - x * r;
}

#define SB0() __builtin_amdgcn_sched_barrier(0)
#define BAR() __builtin_amdgcn_s_barrier()
#define VMW(NN) asm volatile("s_waitcnt vmcnt(%0)" ::"n"(NN) : "memory")

// R5 epilogue (all GEMMs): operands SWAPPED -- mfma(b, a, acc) -> lane
// holds 4 CONSECUTIVE columns -> float4/ushort4 stores.
template <bool OUT_F32>
__device__ __forceinline__ void store4(void* Cv, int N, int row, int col0,
                                       const f32x4& av, const float4& bv) {
  float g0 = gelu_fast(av[0] + bv.x);
  float g1 = gelu_fast(av[1] + bv.y);
  float g2 = gelu_fast(av[2] + bv.z);
  float g3 = gelu_fast(av[3] + bv.w);
  if (OUT_F32) {
    float4 o = {g0, g1, g2, g3};
    *(float4*)&(((float*)Cv)[(size_t)row * N + col0]) = o;
  } else {
    ushort4 o;
    o.x = f2bf(g0); o.y = f2bf(g1); o.z = f2bf(g2); o.w = f2bf(g3);
    *(ushort4*)&(((ushort*)Cv)[(size_t)row * N + col0]) = o;
  }
}

// =====================================================================
// Triple-buffered 1-barrier-per-tile GEMM: BM=256, 8 waves (2M x 4N),
// BK=64, BN in {64,128}. R7 wall-stripped. Verified 795 TF on L0 --
// do not touch.
// =====================================================================
template <int BN, bool OUT_F32>
__global__ __launch_bounds__(512, 2)
void gemm_pipe3(const ushort* __restrict__ A, const ushort* __restrict__ Bw,
                const float* __restrict__ bias, void* __restrict__ Cv,
                int M, int N, int K) {
  constexpr int BM = 256;
  constexpr int WN = BN / 4;             // 16 or 32
  constexpr int FM = 8;
  constexpr int FN = WN / 16;            // 1 or 2
  constexpr int HM = 4;
  constexpr int HN = 1;
  constexpr int SA = 4;
  constexpr int SB = BN / 64;
  constexpr int L = SA + SB;
  constexpr int TILE_USH = (BM + BN) * 64;

  __shared__ ushort lds[3 * TILE_USH];

  const int t = threadIdx.x;
  const int lane = t & 63, wid = t >> 6;
  const int wr = wid >> 2, wc = wid & 3;
  const int l15 = lane & 15, lhi = lane >> 4;

  const int gx = gridDim.x;
  const int nwg = gx * gridDim.y;
  int lin = blockIdx.y * gx + blockIdx.x;
  lin = (lin & 7) * (nwg >> 3) + (lin >> 3);  // XCD chunked (nwg % 8 == 0)
  const int bm0 = (lin / gx) * BM, bn0 = (lin % gx) * BN;

  const int NT = K >> 6;

  const int srow = t >> 3;
  const int scol = ((t & 7) ^ ((t >> 3) & 7)) * 8;

  auto stage = [&](int tile, int buf) {
    ushort* tb = &lds[buf * TILE_USH];
    const int kt = tile * 64;
#pragma unroll
    for (int c = 0; c < SA; ++c) {
      const int lr = c * 64 + srow;
      gload_lds16(A + (size_t)(bm0 + lr) * K + kt + scol,
                  &tb[lr * 64 + (t & 7) * 8]);
    }
#pragma unroll
    for (int c = 0; c < SB; ++c) {
      const int lr = c * 64 + srow;
      gload_lds16(Bw + (size_t)(bn0 + lr) * K + kt + scol,
                  &tb[BM * 64 + lr * 64 + (t & 7) * 8]);
    }
  };

  bf16x8 a[HM][2], b[HN][2];
  f32x4 acc[FM][FN] = {};

  auto loadA = [&](const ushort* tb, int mh) {
#pragma unroll
    for (int mi = 0; mi < HM; ++mi) {
      const int row = wr * 128 + (mh * HM + mi) * 16 + l15;
#pragma unroll
      for (int kh = 0; kh < 2; ++kh)
        a[mi][kh] =
            *(const bf16x8*)&tb[row * 64 + ((kh * 4 + lhi) ^ (l15 & 7)) * 8];
    }
  };
  auto loadB = [&](const ushort* tb, int nh) {
#pragma unroll
    for (int ni = 0; ni < HN; ++ni) {
      const int row = wc * WN + (nh * HN + ni) * 16 + l15;
#pragma unroll
      for (int kh = 0; kh < 2; ++kh)
        b[ni][kh] = *(const bf16x8*)&tb[BM * 64 + row * 64 +
                                        ((kh * 4 + lhi) ^ (l15 & 7)) * 8];
    }
  };

#define MFMA_(MH, NH)                                                        \
  {                                                                          \
    _Pragma("unroll") for (int kh = 0; kh < 2; ++kh)                         \
    _Pragma("unroll") for (int mi = 0; mi < HM; ++mi)                        \
    _Pragma("unroll") for (int ni = 0; ni < HN; ++ni)                        \
      acc[(MH) * HM + mi][(NH) * HN + ni] =                                  \
          __builtin_amdgcn_mfma_f32_16x16x32_bf16(                           \
              b[ni][kh], a[mi][kh], acc[(MH) * HM + mi][(NH) * HN + ni],     \
              0, 0, 0);                                                      \
  }

  stage(0, 0);
  stage(1, 1);
  VMW(L);
  BAR();

  int buf = 0, sbuf = 2;
  for (int tt = 0; tt < NT; ++tt) {
    const bool more = (tt + 2 < NT);
    if (more) stage(tt + 2, sbuf);
    const ushort* tb = &lds[buf * TILE_USH];
    if constexpr (FN == 2) {
      loadA(tb, 0); loadB(tb, 0);
      MFMA_(0, 0);
      loadB(tb, 1);
      MFMA_(0, 1);
      loadA(tb, 1);
      MFMA_(1, 1);
      loadB(tb, 0);
      MFMA_(1, 0);
    } else {
      loadA(tb, 0); loadB(tb, 0);
      MFMA_(0, 0);
      loadA(tb, 1);
      MFMA_(1, 0);
    }
    if (more) { VMW(L); } else { VMW(0); }
    BAR();
    buf = (buf == 2) ? 0 : buf + 1;
    sbuf = (sbuf == 2) ? 0 : sbuf + 1;
  }
#undef MFMA_

#pragma unroll
  for (int m = 0; m < FM; ++m) {
    const int row = bm0 + wr * 128 + m * 16 + l15;
#pragma unroll
    for (int n = 0; n < FN; ++n) {
      const int col0 = bn0 + wc * WN + n * 16 + lhi * 4;
      const float4 bv = *(const float4*)&bias[col0];
      store4<OUT_F32>(Cv, N, row, col0, acc[m][n], bv);
    }
  }
}

// =====================================================================
// R11: gemm_8p4 -- fine 4-phase variant of the verified 8p2. SAME stage
// targets, SAME VMW(4) ledger, SAME single SB0 at the buffer-death
// barrier. Only change: reads/MFMA redistributed into 4 quadrant phases
// with m201's {reads | stage | BAR | 16-MFMA | BAR} rhythm (m196: the
// fine per-phase interleave is the lever; coarse split with same vmcnt
// is not). No other SB0/LGKM0 (R7: walls cost ~15%; C++ dataflow makes
// the compiler's own lgkm waits sufficient for RAW on LDS reads).
//
// Hazard ledger (identical to 8p2's):
//  * RAW: VMW(4) at ph4 end: outstanding = B0,B1(J+1)[4] + A0,A1(J+2)[4]
//    -> retires B(J+1); A(J+1) retired at tile J-1's VMW. BAR(b) makes
//    it all-waves. Tile J+1's ph1 reads covered.             [checked]
//  * WAR: stageA(J+2) writes tb's A region after ph3's closing BAR;
//    every wave's tb reads (A0 ph1, B0 ph1, B1 ph2, A1 ph3) have
//    consuming MFMAs before that BAR (compiler lgkm waits), SB0 walls
//    them above it. stageB(J+1) writes sb = other buffer, dead since
//    tile J-1 end.                                           [checked]
//  * Tails: !s2 -> no A-stage -> VMW(0) drains B(J+1). Last tile no-op.
//  * All BARs in uniform control flow (s1/s2 wave-uniform).
// =====================================================================
template <bool OUT_F32>
__global__ __launch_bounds__(512, 2)
void gemm_8p4(const ushort* __restrict__ A, const ushort* __restrict__ Bw,
              const float* __restrict__ bias, void* __restrict__ Cv,
              int M, int N, int K) {
  constexpr int BM = 256;
  constexpr int BN = 256;
  constexpr int TILE_USH = (BM + BN) * 64;

  __shared__ ushort lds[2 * TILE_USH];

  const int t = threadIdx.x;
  const int lane = t & 63, wid = t >> 6;
  const int wr = wid >> 2, wc = wid & 3;
  const int l15 = lane & 15, lhi = lane >> 4;

  const int gx = gridDim.x;
  const int nwg = gx * gridDim.y;
  int lin = blockIdx.y * gx + blockIdx.x;
  lin = (lin & 7) * (nwg >> 3) + (lin >> 3);  // nwg=256, %8==0
  const int bm0 = (lin / gx) * BM, bn0 = (lin % gx) * BN;

  const int NT = K >> 6;

  const int srow = t >> 3;
  const int scol = ((t & 7) ^ ((t >> 3) & 7)) * 8;

  auto stageA = [&](ushort* tb, int kt, int h) {
#pragma unroll
    for (int c = 0; c < 2; ++c) {
      const int lr = h * 128 + c * 64 + srow;
      gload_lds16(A + (size_t)(bm0 + lr) * K + kt * 64 + scol,
                  &tb[lr * 64 + (t & 7) * 8]);
    }
  };
  auto stageB = [&](ushort* tb, int kt, int h) {
#pragma unroll
    for (int c = 0; c < 2; ++c) {
      const int lr = h * 128 + c * 64 + srow;
      gload_lds16(Bw + (size_t)(bn0 + lr) * K + kt * 64 + scol,
                  &tb[BM * 64 + lr * 64 + (t & 7) * 8]);
    }
  };

  bf16x8 a[2][4][2];   // [mh][mi][kh]
  bf16x8 b[2][2][2];   // [nh][ni][kh]
  f32x4 acc[8][4] = {};

  auto loadA = [&](const ushort* tb, int mh) {
#pragma unroll
    for (int mi = 0; mi < 4; ++mi) {
      const int row = wr * 128 + mh * 64 + mi * 16 + l15;
#pragma unroll
      for (int kh = 0; kh < 2; ++kh)
        a[mh][mi][kh] =
            *(const bf16x8*)&tb[row * 64 + ((kh * 4 + lhi) ^ (l15 & 7)) * 8];
    }
  };
  auto loadB = [&](const ushort* tb, int nh) {
#pragma unroll
    for (int ni = 0; ni < 2; ++ni) {
      const int row = wc * 64 + nh * 32 + ni * 16 + l15;
#pragma unroll
      for (int kh = 0; kh < 2; ++kh)
        b[nh][ni][kh] = *(const bf16x8*)&tb[BM * 64 + row * 64 +
                                            ((kh * 4 + lhi) ^ (l15 & 7)) * 8];
    }
  };

#define MFMA_(MH, NH)                                                        \
  {                                                                          \
    __builtin_amdgcn_s_setprio(1);                                           \
    _Pragma("unroll") for (int kh = 0; kh < 2; ++kh)                         \
    _Pragma("unroll") for (int mi = 0; mi < 4; ++mi)                         \
    _Pragma("unroll") for (int ni = 0; ni < 2; ++ni)                         \
      acc[(MH) * 4 + mi][(NH) * 2 + ni] =                                    \
          __builtin_amdgcn_mfma_f32_16x16x32_bf16(                           \
              b[(NH)][ni][kh], a[(MH)][mi][kh],                              \
              acc[(MH) * 4 + mi][(NH) * 2 + ni], 0, 0, 0);                   \
    __builtin_amdgcn_s_setprio(0);                                           \
  }

  // prologue: tile0 full + tile1 A-halves; VMW(4) -> tile0 landed,
  // A(1) in flight (steady-state stream order).
  {
    ushort* b0 = &lds[0];
    ushort* b1 = &lds[TILE_USH];
    stageA(b0, 0, 0); stageA(b0, 0, 1);
    stageB(b0, 0, 0); stageB(b0, 0, 1);
    stageA(b1, 1, 0); stageA(b1, 1, 1);
    VMW(4);
    BAR();
  }

  for (int J = 0; J < NT; ++J) {
    const ushort* tb = &lds[(J & 1) * TILE_USH];
    ushort* cb = &lds[(J & 1) * TILE_USH];          // A(J+2) into dead region
    ushort* sb = &lds[((J + 1) & 1) * TILE_USH];    // B(J+1)
    const bool s1 = (J + 1) < NT;
    const bool s2 = (J + 2) < NT;

    // ph1: A0+B0 reads (12) | stage B0(J+1) | Q(0,0)
    loadA(tb, 0);
    loadB(tb, 0);
    if (s1) stageB(sb, J + 1, 0);
    BAR();
    MFMA_(0, 0);
    BAR();

    // ph2: B1 reads (4) | stage B1(J+1) | Q(0,1)
    loadB(tb, 1);
    if (s1) stageB(sb, J + 1, 1);
    BAR();
    MFMA_(0, 1);
    BAR();

    // ph3: A1 reads (8) | Q(1,1); closing BAR = tb fully read (death)
    loadA(tb, 1);
    BAR();
    MFMA_(1, 1);
    SB0();   // keep all tb reads + their lgkm waits above the death BAR
    BAR();   // tb A-region now globally dead

    // ph4: stage A(J+2) into dead region | Q(1,0) pure-reg | counted wait
    if (s2) { stageA(cb, J + 2, 0); stageA(cb, J + 2, 1); }
    MFMA_(1, 0);
    if (s2) { VMW(4); } else { VMW(0); }
    BAR();   // publish staged halves
  }
#undef MFMA_

#pragma unroll
  for (int m = 0; m < 8; ++m) {
    const int row = bm0 + wr * 128 + m * 16 + l15;
#pragma unroll
    for (int n = 0; n < 4; ++n) {
      const int col0 = bn0 + wc * 64 + n * 16 + lhi * 4;
      const float4 bv = *(const float4*)&bias[col0];
      store4<OUT_F32>(Cv, N, row, col0, acc[m][n], bv);
    }
  }
}

// ---------- 2-phase GEMM for small layers (R2 structure; R5 epilogue) ----------
template <int BM, int BN, bool OUT_F32>
__global__ __launch_bounds__(256, 4)
void gemm_bt_bias_gelu(const ushort* __restrict__ A, const ushort* __restrict__ Bw,
                       const float* __restrict__ bias, void* __restrict__ Cv,
                       int M, int N, int K) {
  constexpr int WTM = BM / 32;
  constexpr int WTN = BN / 32;
  __shared__ ushort As[BM * 64];
  __shared__ ushort Bs[BN * 64];
  const int t = threadIdx.x;
  const int lane = t & 63, wid = t >> 6;
  const int wr = wid >> 1, wc = wid & 1;
  const int l15 = lane & 15, lhi = lane >> 4;

  const int gx = gridDim.x;
  const int nwg = gx * gridDim.y;
  int lin = blockIdx.y * gx + blockIdx.x;
  if ((nwg & 7) == 0) lin = (lin & 7) * (nwg >> 3) + (lin >> 3);
  const int bm0 = (lin / gx) * BM, bn0 = (lin % gx) * BN;

  const ushort* Abase = A + (size_t)bm0 * K;
  const ushort* Bbase = Bw + (size_t)bn0 * K;

  f32x4 acc[WTM][WTN] = {};

  for (int kt = 0; kt < K; kt += 64) {
#pragma unroll
    for (int i = 0; i < BM / 32; ++i) {
      int c = i * 256 + t;
      int r = c >> 3, c8 = c & 7;
      gload_lds16(Abase + (size_t)r * K + kt + c8 * 8, &As[c * 8]);
    }
#pragma unroll
    for (int i = 0; i < BN / 32; ++i) {
      int c = i * 256 + t;
      int r = c >> 3, c8 = c & 7;
      gload_lds16(Bbase + (size_t)r * K + kt + c8 * 8, &Bs[c * 8]);
    }
    asm volatile("s_waitcnt vmcnt(0)" ::: "memory");
    __syncthreads();
#pragma unroll
    for (int kk = 0; kk < 64; kk += 32) {
      bf16x8 af[WTM], bfr[WTN];
#pragma unroll
      for (int m = 0; m < WTM; ++m)
        af[m] = *(const bf16x8*)&As[(wr * (BM / 2) + m * 16 + l15) * 64 + kk + lhi * 8];
#pragma unroll
      for (int n = 0; n < WTN; ++n)
        bfr[n] = *(const bf16x8*)&Bs[(wc * (BN / 2) + n * 16 + l15) * 64 + kk + lhi * 8];
#pragma unroll
      for (int m = 0; m < WTM; ++m)
#pragma unroll
        for (int n = 0; n < WTN; ++n)
          acc[m][n] = __builtin_amdgcn_mfma_f32_16x16x32_bf16(bfr[n], af[m], acc[m][n], 0, 0, 0);
    }
    __syncthreads();
  }

#pragma unroll
  for (int m = 0; m < WTM; ++m) {
    const int row = bm0 + wr * (BM / 2) + m * 16 + l15;
#pragma unroll
    for (int n = 0; n < WTN; ++n) {
      const int col0 = bn0 + wc * (BN / 2) + n * 16 + lhi * 4;
      const float4 bv = *(const float4*)&bias[col0];
      store4<OUT_F32>(Cv, N, row, col0, acc[m][n], bv);
    }
  }
}

extern "C" void kernel_launch(void* const* d_in, const int* in_sizes, int n_in,
                              void* d_out, int out_size, void* d_ws, size_t ws_size,
                              hipStream_t stream) {
  const float* z   = (const float*)d_in[0];
  const float* att = (const float*)d_in[1];
  const float* Wptr[7] = {(const float*)d_in[2],  (const float*)d_in[4],
                          (const float*)d_in[6],  (const float*)d_in[8],
                          (const float*)d_in[10], (const float*)d_in[12],
                          (const float*)d_in[14]};
  const float* bptr[7] = {(const float*)d_in[3],  (const float*)d_in[5],
                          (const float*)d_in[7],  (const float*)d_in[9],
                          (const float*)d_in[11], (const float*)d_in[13],
                          (const float*)d_in[15]};
  const int Ns[7] = {1024, 512, 256, 256, 512, 1024, 2048};
  const int Ks[7] = {2048, 1024, 512, 256, 256, 512, 1024};
  const int M = 8192;

  char* ws = (char*)d_ws;
  ushort* bufA = (ushort*)ws;
  ushort* bufB = (ushort*)(ws + 33554432);
  ushort* qw   = (ushort*)(ws + 33554432 + 16777216);
  float* partials = (float*)(ws + 33554432 + 16777216 + 11141120);

  WDesc wd;
  int cum = 0;
  size_t qoff[7]; size_t qc = 0;
  for (int l = 0; l < 7; ++l) {
    wd.W[l] = Wptr[l];
    int nv = Ns[l] * Ks[l] / 4;
    wd.nvec[l] = nv;
    wd.vcum[l] = cum;
    cum += nv;
    qoff[l] = qc;
    qc += (size_t)Ns[l] * Ks[l];
  }
  wd.vcum[7] = cum;

  const int qblks = (cum + 255) / 256;
  absmean_concat<<<448 + 16384, 256, 0, stream>>>(wd, partials, z, att, bufA);
  quant_final<<<qblks, 256, 0, stream>>>(wd, partials, qw);

  ushort* inb = bufA; ushort* outb = bufB;
  // L0: 8192x1024, K=2048 -> pipe3 <BN=128>, grid (8,32)=256
  gemm_pipe3<128, false><<<dim3(Ns[0] / 128, M / 256), dim3(512), 0, stream>>>(
      inb, qw + qoff[0], bptr[0], outb, M, Ns[0], Ks[0]);
  { ushort* tmp = inb; inb = outb; outb = tmp; }
  // L1: 8192x512, K=1024 -> pipe3 <BN=64>, grid (8,32)=256
  gemm_pipe3<64, false><<<dim3(Ns[1] / 64, M / 256), dim3(512), 0, stream>>>(
      inb, qw + qoff[1], bptr[1], outb, M, Ns[1], Ks[1]);
  { ushort* tmp = inb; inb = outb; outb = tmp; }
  // L2: 8192x256, K=512 -> 2-phase <64,64>
  gemm_bt_bias_gelu<64, 64, false><<<dim3(Ns[2] / 64, M / 64), 256, 0, stream>>>(
      inb, qw + qoff[2], bptr[2], outb, M, Ns[2], Ks[2]);
  { ushort* tmp = inb; inb = outb; outb = tmp; }
  // L3: 8192x256, K=256 -> 2-phase <64,64>
  gemm_bt_bias_gelu<64, 64, false><<<dim3(Ns[3] / 64, M / 64), 256, 0, stream>>>(
      inb, qw + qoff[3], bptr[3], outb, M, Ns[3], Ks[3]);
  { ushort* tmp = inb; inb = outb; outb = tmp; }
  // L4: 8192x512, K=256 -> pipe3 <BN=64>, grid (8,32)=256
  gemm_pipe3<64, false><<<dim3(Ns[4] / 64, M / 256), dim3(512), 0, stream>>>(
      inb, qw + qoff[4], bptr[4], outb, M, Ns[4], Ks[4]);
  { ushort* tmp = inb; inb = outb; outb = tmp; }
  // L5: 8192x1024, K=512 -> pipe3 <BN=128>, grid (8,32)
  gemm_pipe3<128, false><<<dim3(Ns[5] / 128, M / 256), dim3(512), 0, stream>>>(
      inb, qw + qoff[5], bptr[5], outb, M, Ns[5], Ks[5]);
  { ushort* tmp = inb; inb = outb; outb = tmp; }
  // L6: 8192x2048, K=1024 -> gemm_8p4 (R11 fine 4-phase, same ledger as
  // verified 8p2). fp32 out.
  gemm_8p4<true><<<dim3(Ns[6] / 256, M / 256), dim3(512), 0, stream>>>(
      inb, qw + qoff[6], bptr[6], d_out, M, Ns[6], Ks[6]);
}

// Round 12
// 176.504 us; speedup vs baseline: 1.0160x; 1.0160x over previous
//
#include <hip/hip_runtime.h>
#include <hip/hip_bf16.h>
#include <cstdint>

typedef __attribute__((ext_vector_type(8))) __bf16 bf16x8;
typedef __attribute__((ext_vector_type(4))) float f32x4;

typedef __attribute__((address_space(1))) const void g_void;
typedef __attribute__((address_space(3))) void l_void;

__device__ __forceinline__ void gload_lds16(const void* g, void* l) {
  __builtin_amdgcn_global_load_lds((g_void*)(uintptr_t)g,
                                   (l_void*)(uint32_t)(uintptr_t)l, 16, 0, 0);
}

__device__ __forceinline__ ushort f2bf(float f) {
  union { float f; uint32_t u; } v; v.f = f;
  uint32_t r = v.u + 0x7fffu + ((v.u >> 16) & 1u);
  return (ushort)(r >> 16);
}

struct WDesc {
  const float* W[7];
  int nvec[7];
  int vcum[8];
};

// ---------- R10 prep: 2 fused kernels (verified) ----------
__global__ void absmean_concat(WDesc wd, float* __restrict__ partials,
                               const float* __restrict__ z,
                               const float* __restrict__ att,
                               ushort* __restrict__ cat) {
  const int b = blockIdx.x;
  const int t = threadIdx.x;
  if (b < 448) {
    __shared__ float red[256];
    const int layer = b >> 6, blk = b & 63;
    const float4* W = (const float4*)wd.W[layer];
    const int nv = wd.nvec[layer];
    float s = 0.f;
    for (int i = blk * 256 + t; i < nv; i += 64 * 256) {
      float4 w = W[i];
      s += fabsf(w.x) + fabsf(w.y) + fabsf(w.z) + fabsf(w.w);
    }
    red[t] = s;
    __syncthreads();
    for (int o = 128; o > 0; o >>= 1) {
      if (t < o) red[t] += red[t + o];
      __syncthreads();
    }
    if (t == 0) partials[layer * 64 + blk] = red[0];
  } else {
    const int bc = b - 448;
    const int row = bc >> 1;
    const int h = bc & 1;
    const float* src = (h ? att : z) + (size_t)row * 1024 + t * 4;
    float4 a = *(const float4*)src;
    ushort4 o;
    o.x = f2bf(a.x); o.y = f2bf(a.y); o.z = f2bf(a.z); o.w = f2bf(a.w);
    *(ushort4*)(cat + (size_t)row * 2048 + h * 1024 + t * 4) = o;
  }
}

__global__ void quant_final(WDesc wd, const float* __restrict__ partials,
                            ushort* __restrict__ qw) {
  __shared__ float igs;
  const int t = threadIdx.x;
  const int v = blockIdx.x * 256 + t;
  const int v0 = blockIdx.x * 256;
  int layer = 0;
#pragma unroll
  for (int i = 1; i < 7; ++i) layer += (v0 >= wd.vcum[i]);
  if (t < 64) {
    float x = partials[layer * 64 + t];
    for (int o = 32; o > 0; o >>= 1) x += __shfl_down(x, o, 64);
    if (t == 0) {
      float mean = x / (float)(wd.nvec[layer] * 4);
      igs = 1.0f / (mean + 1e-8f);
    }
  }
  __syncthreads();
  if (v >= wd.vcum[7]) return;
  const float g = igs;
  const int lv = v - wd.vcum[layer];
  float4 w = ((const float4*)wd.W[layer])[lv];
  ushort4 o;
  o.x = f2bf(fmaxf(-1.f, fminf(1.f, rintf(w.x * g))));
  o.y = f2bf(fmaxf(-1.f, fminf(1.f, rintf(w.y * g))));
  o.z = f2bf(fmaxf(-1.f, fminf(1.f, rintf(w.z * g))));
  o.w = f2bf(fmaxf(-1.f, fminf(1.f, rintf(w.w * g))));
  ((ushort4*)qw)[v] = o;
}

// ---------- fast GELU (tanh form, branch-free) ----------
__device__ __forceinline__ float gelu_fast(float x) {
  float x2 = x * x;
  float u = x * fmaf(x2, 0.0356774081f, 0.7978845608f);
  float e = exp2f(u * 2.8853900818f);
  float r = __builtin_amdgcn_rcpf(e + 1.0f);
  return x - x * r;
}

#define SB0() __builtin_amdgcn_sched_barrier(0)
#define BAR() __builtin_amdgcn_s_barrier()
#define VMW(NN) asm volatile("s_waitcnt vmcnt(%0)" ::"n"(NN) : "memory")

// R5 epilogue (all GEMMs): operands SWAPPED -- mfma(b, a, acc) -> lane
// holds 4 CONSECUTIVE columns -> float4/ushort4 stores.
template <bool OUT_F32>
__device__ __forceinline__ void store4(void* Cv, int N, int row, int col0,
                                       const f32x4& av, const float4& bv) {
  float g0 = gelu_fast(av[0] + bv.x);
  float g1 = gelu_fast(av[1] + bv.y);
  float g2 = gelu_fast(av[2] + bv.z);
  float g3 = gelu_fast(av[3] + bv.w);
  if (OUT_F32) {
    float4 o = {g0, g1, g2, g3};
    *(float4*)&(((float*)Cv)[(size_t)row * N + col0]) = o;
  } else {
    ushort4 o;
    o.x = f2bf(g0); o.y = f2bf(g1); o.z = f2bf(g2); o.w = f2bf(g3);
    *(ushort4*)&(((ushort*)Cv)[(size_t)row * N + col0]) = o;
  }
}

// =====================================================================
// Triple-buffered 1-barrier-per-tile GEMM: BM=256, 8 waves (2M x 4N),
// BK=64, BN in {64,128}. R7 wall-stripped. Verified ~792 TF on L0.
// SESSION NOTE: 7 schedule variants tested; only wall-stripping moved
// the needle (m141/m190 confirmed). Do not touch.
// =====================================================================
template <int BN, bool OUT_F32>
__global__ __launch_bounds__(512, 2)
void gemm_pipe3(const ushort* __restrict__ A, const ushort* __restrict__ Bw,
                const float* __restrict__ bias, void* __restrict__ Cv,
                int M, int N, int K) {
  constexpr int BM = 256;
  constexpr int WN = BN / 4;             // 16 or 32
  constexpr int FM = 8;
  constexpr int FN = WN / 16;            // 1 or 2
  constexpr int HM = 4;
  constexpr int HN = 1;
  constexpr int SA = 4;
  constexpr int SB = BN / 64;
  constexpr int L = SA + SB;
  constexpr int TILE_USH = (BM + BN) * 64;

  __shared__ ushort lds[3 * TILE_USH];

  const int t = threadIdx.x;
  const int lane = t & 63, wid = t >> 6;
  const int wr = wid >> 2, wc = wid & 3;
  const int l15 = lane & 15, lhi = lane >> 4;

  const int gx = gridDim.x;
  const int nwg = gx * gridDim.y;
  int lin = blockIdx.y * gx + blockIdx.x;
  lin = (lin & 7) * (nwg >> 3) + (lin >> 3);  // XCD chunked (nwg % 8 == 0)
  const int bm0 = (lin / gx) * BM, bn0 = (lin % gx) * BN;

  const int NT = K >> 6;

  const int srow = t >> 3;
  const int scol = ((t & 7) ^ ((t >> 3) & 7)) * 8;

  auto stage = [&](int tile, int buf) {
    ushort* tb = &lds[buf * TILE_USH];
    const int kt = tile * 64;
#pragma unroll
    for (int c = 0; c < SA; ++c) {
      const int lr = c * 64 + srow;
      gload_lds16(A + (size_t)(bm0 + lr) * K + kt + scol,
                  &tb[lr * 64 + (t & 7) * 8]);
    }
#pragma unroll
    for (int c = 0; c < SB; ++c) {
      const int lr = c * 64 + srow;
      gload_lds16(Bw + (size_t)(bn0 + lr) * K + kt + scol,
                  &tb[BM * 64 + lr * 64 + (t & 7) * 8]);
    }
  };

  bf16x8 a[HM][2], b[HN][2];
  f32x4 acc[FM][FN] = {};

  auto loadA = [&](const ushort* tb, int mh) {
#pragma unroll
    for (int mi = 0; mi < HM; ++mi) {
      const int row = wr * 128 + (mh * HM + mi) * 16 + l15;
#pragma unroll
      for (int kh = 0; kh < 2; ++kh)
        a[mi][kh] =
            *(const bf16x8*)&tb[row * 64 + ((kh * 4 + lhi) ^ (l15 & 7)) * 8];
    }
  };
  auto loadB = [&](const ushort* tb, int nh) {
#pragma unroll
    for (int ni = 0; ni < HN; ++ni) {
      const int row = wc * WN + (nh * HN + ni) * 16 + l15;
#pragma unroll
      for (int kh = 0; kh < 2; ++kh)
        b[ni][kh] = *(const bf16x8*)&tb[BM * 64 + row * 64 +
                                        ((kh * 4 + lhi) ^ (l15 & 7)) * 8];
    }
  };

#define MFMA_(MH, NH)                                                        \
  {                                                                          \
    _Pragma("unroll") for (int kh = 0; kh < 2; ++kh)                         \
    _Pragma("unroll") for (int mi = 0; mi < HM; ++mi)                        \
    _Pragma("unroll") for (int ni = 0; ni < HN; ++ni)                        \
      acc[(MH) * HM + mi][(NH) * HN + ni] =                                  \
          __builtin_amdgcn_mfma_f32_16x16x32_bf16(                           \
              b[ni][kh], a[mi][kh], acc[(MH) * HM + mi][(NH) * HN + ni],     \
              0, 0, 0);                                                      \
  }

  stage(0, 0);
  stage(1, 1);
  VMW(L);
  BAR();

  int buf = 0, sbuf = 2;
  for (int tt = 0; tt < NT; ++tt) {
    const bool more = (tt + 2 < NT);
    if (more) stage(tt + 2, sbuf);
    const ushort* tb = &lds[buf * TILE_USH];
    if constexpr (FN == 2) {
      loadA(tb, 0); loadB(tb, 0);
      MFMA_(0, 0);
      loadB(tb, 1);
      MFMA_(0, 1);
      loadA(tb, 1);
      MFMA_(1, 1);
      loadB(tb, 0);
      MFMA_(1, 0);
    } else {
      loadA(tb, 0); loadB(tb, 0);
      MFMA_(0, 0);
      loadA(tb, 1);
      MFMA_(1, 0);
    }
    if (more) { VMW(L); } else { VMW(0); }
    BAR();
    buf = (buf == 2) ? 0 : buf + 1;
    sbuf = (sbuf == 2) ? 0 : sbuf + 1;
  }
#undef MFMA_

#pragma unroll
  for (int m = 0; m < FM; ++m) {
    const int row = bm0 + wr * 128 + m * 16 + l15;
#pragma unroll
    for (int n = 0; n < FN; ++n) {
      const int col0 = bn0 + wc * WN + n * 16 + lhi * 4;
      const float4 bv = *(const float4*)&bias[col0];
      store4<OUT_F32>(Cv, N, row, col0, acc[m][n], bv);
    }
  }
}

// =====================================================================
// R6/R7 gemm_8p2: deep-pipelined 256^2 GEMM, 2 barriers/tile, compiler-
// managed lgkm. Hazard ledger: RAW via VMW(4)+BAR(b) (outstanding at
// wait = B0,B1(J+1) behind A0,A1(J+2) -> retires B(J+1); A(J+1) retired
// at tile J-1's wait); WAR via SB0-walled BAR(a) buffer death; tails
// via VMW(0). R10-verified ~43 us on L6 (R11's fine 4-phase variant
// measured 45.5 -> reverted). Do not touch.
// =====================================================================
template <bool OUT_F32>
__global__ __launch_bounds__(512, 2)
void gemm_8p2(const ushort* __restrict__ A, const ushort* __restrict__ Bw,
              const float* __restrict__ bias, void* __restrict__ Cv,
              int M, int N, int K) {
  constexpr int BM = 256;
  constexpr int BN = 256;
  constexpr int TILE_USH = (BM + BN) * 64;

  __shared__ ushort lds[2 * TILE_USH];

  const int t = threadIdx.x;
  const int lane = t & 63, wid = t >> 6;
  const int wr = wid >> 2, wc = wid & 3;
  const int l15 = lane & 15, lhi = lane >> 4;

  const int gx = gridDim.x;
  const int nwg = gx * gridDim.y;
  int lin = blockIdx.y * gx + blockIdx.x;
  lin = (lin & 7) * (nwg >> 3) + (lin >> 3);  // nwg=256, %8==0
  const int bm0 = (lin / gx) * BM, bn0 = (lin % gx) * BN;

  const int NT = K >> 6;

  const int srow = t >> 3;
  const int scol = ((t & 7) ^ ((t >> 3) & 7)) * 8;

  auto stageA = [&](ushort* tb, int kt, int h) {
#pragma unroll
    for (int c = 0; c < 2; ++c) {
      const int lr = h * 128 + c * 64 + srow;
      gload_lds16(A + (size_t)(bm0 + lr) * K + kt * 64 + scol,
                  &tb[lr * 64 + (t & 7) * 8]);
    }
  };
  auto stageB = [&](ushort* tb, int kt, int h) {
#pragma unroll
    for (int c = 0; c < 2; ++c) {
      const int lr = h * 128 + c * 64 + srow;
      gload_lds16(Bw + (size_t)(bn0 + lr) * K + kt * 64 + scol,
                  &tb[BM * 64 + lr * 64 + (t & 7) * 8]);
    }
  };

  bf16x8 a[2][4][2];   // [mh][mi][kh]
  bf16x8 b[2][2][2];   // [nh][ni][kh]
  f32x4 acc[8][4] = {};

  auto loadA = [&](const ushort* tb, int mh) {
#pragma unroll
    for (int mi = 0; mi < 4; ++mi) {
      const int row = wr * 128 + mh * 64 + mi * 16 + l15;
#pragma unroll
      for (int kh = 0; kh < 2; ++kh)
        a[mh][mi][kh] =
            *(const bf16x8*)&tb[row * 64 + ((kh * 4 + lhi) ^ (l15 & 7)) * 8];
    }
  };
  auto loadB = [&](const ushort* tb, int nh) {
#pragma unroll
    for (int ni = 0; ni < 2; ++ni) {
      const int row = wc * 64 + nh * 32 + ni * 16 + l15;
#pragma unroll
      for (int kh = 0; kh < 2; ++kh)
        b[nh][ni][kh] = *(const bf16x8*)&tb[BM * 64 + row * 64 +
                                            ((kh * 4 + lhi) ^ (l15 & 7)) * 8];
    }
  };

#define MFMA_(MH, NH)                                                        \
  {                                                                          \
    __builtin_amdgcn_s_setprio(1);                                           \
    _Pragma("unroll") for (int kh = 0; kh < 2; ++kh)                         \
    _Pragma("unroll") for (int mi = 0; mi < 4; ++mi)                         \
    _Pragma("unroll") for (int ni = 0; ni < 2; ++ni)                         \
      acc[(MH) * 4 + mi][(NH) * 2 + ni] =                                    \
          __builtin_amdgcn_mfma_f32_16x16x32_bf16(                           \
              b[(NH)][ni][kh], a[(MH)][mi][kh],                              \
              acc[(MH) * 4 + mi][(NH) * 2 + ni], 0, 0, 0);                   \
    __builtin_amdgcn_s_setprio(0);                                           \
  }

  {
    ushort* b0 = &lds[0];
    ushort* b1 = &lds[TILE_USH];
    stageA(b0, 0, 0); stageA(b0, 0, 1);
    stageB(b0, 0, 0); stageB(b0, 0, 1);
    stageA(b1, 1, 0); stageA(b1, 1, 1);
    VMW(4);
    BAR();
  }

  for (int J = 0; J < NT; ++J) {
    const ushort* tb = &lds[(J & 1) * TILE_USH];
    ushort* cb = &lds[(J & 1) * TILE_USH];
    ushort* sb = &lds[((J + 1) & 1) * TILE_USH];
    const bool s1 = (J + 1) < NT;
    const bool s2 = (J + 2) < NT;

    loadA(tb, 0);
    loadB(tb, 0);
    if (s1) stageB(sb, J + 1, 0);
    MFMA_(0, 0);
    loadA(tb, 1);
    loadB(tb, 1);
    if (s1) stageB(sb, J + 1, 1);
    MFMA_(1, 1);
    SB0();   // wall: keep all tb reads + their MFMAs above BAR(a)
    BAR();   // (a) tb A-region now globally dead
    if (s2) { stageA(cb, J + 2, 0); stageA(cb, J + 2, 1); }
    MFMA_(0, 1);
    MFMA_(1, 0);
    if (s2) { VMW(4); } else { VMW(0); }
    BAR();   // (b) publish staged halves
  }
#undef MFMA_

#pragma unroll
  for (int m = 0; m < 8; ++m) {
    const int row = bm0 + wr * 128 + m * 16 + l15;
#pragma unroll
    for (int n = 0; n < 4; ++n) {
      const int col0 = bn0 + wc * 64 + n * 16 + lhi * 4;
      const float4 bv = *(const float4*)&bias[col0];
      store4<OUT_F32>(Cv, N, row, col0, acc[m][n], bv);
    }
  }
}

// ---------- 2-phase GEMM for small layers (R2 structure; R5 epilogue) ----------
template <int BM, int BN, bool OUT_F32>
__global__ __launch_bounds__(256, 4)
void gemm_bt_bias_gelu(const ushort* __restrict__ A, const ushort* __restrict__ Bw,
                       const float* __restrict__ bias, void* __restrict__ Cv,
                       int M, int N, int K) {
  constexpr int WTM = BM / 32;
  constexpr int WTN = BN / 32;
  __shared__ ushort As[BM * 64];
  __shared__ ushort Bs[BN * 64];
  const int t = threadIdx.x;
  const int lane = t & 63, wid = t >> 6;
  const int wr = wid >> 1, wc = wid & 1;
  const int l15 = lane & 15, lhi = lane >> 4;

  const int gx = gridDim.x;
  const int nwg = gx * gridDim.y;
  int lin = blockIdx.y * gx + blockIdx.x;
  if ((nwg & 7) == 0) lin = (lin & 7) * (nwg >> 3) + (lin >> 3);
  const int bm0 = (lin / gx) * BM, bn0 = (lin % gx) * BN;

  const ushort* Abase = A + (size_t)bm0 * K;
  const ushort* Bbase = Bw + (size_t)bn0 * K;

  f32x4 acc[WTM][WTN] = {};

  for (int kt = 0; kt < K; kt += 64) {
#pragma unroll
    for (int i = 0; i < BM / 32; ++i) {
      int c = i * 256 + t;
      int r = c >> 3, c8 = c & 7;
      gload_lds16(Abase + (size_t)r * K + kt + c8 * 8, &As[c * 8]);
    }
#pragma unroll
    for (int i = 0; i < BN / 32; ++i) {
      int c = i * 256 + t;
      int r = c >> 3, c8 = c & 7;
      gload_lds16(Bbase + (size_t)r * K + kt + c8 * 8, &Bs[c * 8]);
    }
    asm volatile("s_waitcnt vmcnt(0)" ::: "memory");
    __syncthreads();
#pragma unroll
    for (int kk = 0; kk < 64; kk += 32) {
      bf16x8 af[WTM], bfr[WTN];
#pragma unroll
      for (int m = 0; m < WTM; ++m)
        af[m] = *(const bf16x8*)&As[(wr * (BM / 2) + m * 16 + l15) * 64 + kk + lhi * 8];
#pragma unroll
      for (int n = 0; n < WTN; ++n)
        bfr[n] = *(const bf16x8*)&Bs[(wc * (BN / 2) + n * 16 + l15) * 64 + kk + lhi * 8];
#pragma unroll
      for (int m = 0; m < WTM; ++m)
#pragma unroll
        for (int n = 0; n < WTN; ++n)
          acc[m][n] = __builtin_amdgcn_mfma_f32_16x16x32_bf16(bfr[n], af[m], acc[m][n], 0, 0, 0);
    }
    __syncthreads();
  }

#pragma unroll
  for (int m = 0; m < WTM; ++m) {
    const int row = bm0 + wr * (BM / 2) + m * 16 + l15;
#pragma unroll
    for (int n = 0; n < WTN; ++n) {
      const int col0 = bn0 + wc * (BN / 2) + n * 16 + lhi * 4;
      const float4 bv = *(const float4*)&bias[col0];
      store4<OUT_F32>(Cv, N, row, col0, acc[m][n], bv);
    }
  }
}

extern "C" void kernel_launch(void* const* d_in, const int* in_sizes, int n_in,
                              void* d_out, int out_size, void* d_ws, size_t ws_size,
                              hipStream_t stream) {
  const float* z   = (const float*)d_in[0];
  const float* att = (const float*)d_in[1];
  const float* Wptr[7] = {(const float*)d_in[2],  (const float*)d_in[4],
                          (const float*)d_in[6],  (const float*)d_in[8],
                          (const float*)d_in[10], (const float*)d_in[12],
                          (const float*)d_in[14]};
  const float* bptr[7] = {(const float*)d_in[3],  (const float*)d_in[5],
                          (const float*)d_in[7],  (const float*)d_in[9],
                          (const float*)d_in[11], (const float*)d_in[13],
                          (const float*)d_in[15]};
  const int Ns[7] = {1024, 512, 256, 256, 512, 1024, 2048};
  const int Ks[7] = {2048, 1024, 512, 256, 256, 512, 1024};
  const int M = 8192;

  char* ws = (char*)d_ws;
  ushort* bufA = (ushort*)ws;
  ushort* bufB = (ushort*)(ws + 33554432);
  ushort* qw   = (ushort*)(ws + 33554432 + 16777216);
  float* partials = (float*)(ws + 33554432 + 16777216 + 11141120);

  WDesc wd;
  int cum = 0;
  size_t qoff[7]; size_t qc = 0;
  for (int l = 0; l < 7; ++l) {
    wd.W[l] = Wptr[l];
    int nv = Ns[l] * Ks[l] / 4;
    wd.nvec[l] = nv;
    wd.vcum[l] = cum;
    cum += nv;
    qoff[l] = qc;
    qc += (size_t)Ns[l] * Ks[l];
  }
  wd.vcum[7] = cum;

  const int qblks = (cum + 255) / 256;
  absmean_concat<<<448 + 16384, 256, 0, stream>>>(wd, partials, z, att, bufA);
  quant_final<<<qblks, 256, 0, stream>>>(wd, partials, qw);

  ushort* inb = bufA; ushort* outb = bufB;
  // L0: 8192x1024, K=2048 -> pipe3 <BN=128>, grid (8,32)=256
  gemm_pipe3<128, false><<<dim3(Ns[0] / 128, M / 256), dim3(512), 0, stream>>>(
      inb, qw + qoff[0], bptr[0], outb, M, Ns[0], Ks[0]);
  { ushort* tmp = inb; inb = outb; outb = tmp; }
  // L1: 8192x512, K=1024 -> pipe3 <BN=64>, grid (8,32)=256
  gemm_pipe3<64, false><<<dim3(Ns[1] / 64, M / 256), dim3(512), 0, stream>>>(
      inb, qw + qoff[1], bptr[1], outb, M, Ns[1], Ks[1]);
  { ushort* tmp = inb; inb = outb; outb = tmp; }
  // L2: 8192x256, K=512 -> 2-phase <64,64>
  gemm_bt_bias_gelu<64, 64, false><<<dim3(Ns[2] / 64, M / 64), 256, 0, stream>>>(
      inb, qw + qoff[2], bptr[2], outb, M, Ns[2], Ks[2]);
  { ushort* tmp = inb; inb = outb; outb = tmp; }
  // L3: 8192x256, K=256 -> 2-phase <64,64>
  gemm_bt_bias_gelu<64, 64, false><<<dim3(Ns[3] / 64, M / 64), 256, 0, stream>>>(
      inb, qw + qoff[3], bptr[3], outb, M, Ns[3], Ks[3]);
  { ushort* tmp = inb; inb = outb; outb = tmp; }
  // L4: 8192x512, K=256 -> pipe3 <BN=64>, grid (8,32)=256
  gemm_pipe3<64, false><<<dim3(Ns[4] / 64, M / 256), dim3(512), 0, stream>>>(
      inb, qw + qoff[4], bptr[4], outb, M, Ns[4], Ks[4]);
  { ushort* tmp = inb; inb = outb; outb = tmp; }
  // L5: 8192x1024, K=512 -> pipe3 <BN=128>, grid (8,32)
  gemm_pipe3<128, false><<<dim3(Ns[5] / 128, M / 256), dim3(512), 0, stream>>>(
      inb, qw + qoff[5], bptr[5], outb, M, Ns[5], Ks[5]);
  { ushort* tmp = inb; inb = outb; outb = tmp; }
  // L6: 8192x2048, K=1024 -> gemm_8p2 (R10-verified ~43 us; R11's fine
  // 4-phase measured 45.5 -> reverted). fp32 out.
  gemm_8p2<true><<<dim3(Ns[6] / 256, M / 256), dim3(512), 0, stream>>>(
      inb, qw + qoff[6], bptr[6], d_out, M, Ns[6], Ks[6]);
}

// Round 13
// 173.893 us; speedup vs baseline: 1.0313x; 1.0150x over previous
//
#include <hip/hip_runtime.h>
#include <hip/hip_bf16.h>
#include <cstdint>

typedef __attribute__((ext_vector_type(8))) __bf16 bf16x8;
typedef __attribute__((ext_vector_type(4))) float f32x4;

typedef __attribute__((address_space(1))) const void g_void;
typedef __attribute__((address_space(3))) void l_void;

__device__ __forceinline__ void gload_lds16(const void* g, void* l) {
  __builtin_amdgcn_global_load_lds((g_void*)(uintptr_t)g,
                                   (l_void*)(uint32_t)(uintptr_t)l, 16, 0, 0);
}

__device__ __forceinline__ ushort f2bf(float f) {
  union { float f; uint32_t u; } v; v.f = f;
  uint32_t r = v.u + 0x7fffu + ((v.u >> 16) & 1u);
  return (ushort)(r >> 16);
}

struct WDesc {
  const float* W[7];
  int nvec[7];
  int vcum[8];
};

// ---------- R10 prep: 2 fused kernels (verified) ----------
__global__ void absmean_concat(WDesc wd, float* __restrict__ partials,
                               const float* __restrict__ z,
                               const float* __restrict__ att,
                               ushort* __restrict__ cat) {
  const int b = blockIdx.x;
  const int t = threadIdx.x;
  if (b < 448) {
    __shared__ float red[256];
    const int layer = b >> 6, blk = b & 63;
    const float4* W = (const float4*)wd.W[layer];
    const int nv = wd.nvec[layer];
    float s = 0.f;
    for (int i = blk * 256 + t; i < nv; i += 64 * 256) {
      float4 w = W[i];
      s += fabsf(w.x) + fabsf(w.y) + fabsf(w.z) + fabsf(w.w);
    }
    red[t] = s;
    __syncthreads();
    for (int o = 128; o > 0; o >>= 1) {
      if (t < o) red[t] += red[t + o];
      __syncthreads();
    }
    if (t == 0) partials[layer * 64 + blk] = red[0];
  } else {
    const int bc = b - 448;
    const int row = bc >> 1;
    const int h = bc & 1;
    const float* src = (h ? att : z) + (size_t)row * 1024 + t * 4;
    float4 a = *(const float4*)src;
    ushort4 o;
    o.x = f2bf(a.x); o.y = f2bf(a.y); o.z = f2bf(a.z); o.w = f2bf(a.w);
    *(ushort4*)(cat + (size_t)row * 2048 + h * 1024 + t * 4) = o;
  }
}

__global__ void quant_final(WDesc wd, const float* __restrict__ partials,
                            ushort* __restrict__ qw) {
  __shared__ float igs;
  const int t = threadIdx.x;
  const int v = blockIdx.x * 256 + t;
  const int v0 = blockIdx.x * 256;
  int layer = 0;
#pragma unroll
  for (int i = 1; i < 7; ++i) layer += (v0 >= wd.vcum[i]);
  if (t < 64) {
    float x = partials[layer * 64 + t];
    for (int o = 32; o > 0; o >>= 1) x += __shfl_down(x, o, 64);
    if (t == 0) {
      float mean = x / (float)(wd.nvec[layer] * 4);
      igs = 1.0f / (mean + 1e-8f);
    }
  }
  __syncthreads();
  if (v >= wd.vcum[7]) return;
  const float g = igs;
  const int lv = v - wd.vcum[layer];
  float4 w = ((const float4*)wd.W[layer])[lv];
  ushort4 o;
  o.x = f2bf(fmaxf(-1.f, fminf(1.f, rintf(w.x * g))));
  o.y = f2bf(fmaxf(-1.f, fminf(1.f, rintf(w.y * g))));
  o.z = f2bf(fmaxf(-1.f, fminf(1.f, rintf(w.z * g))));
  o.w = f2bf(fmaxf(-1.f, fminf(1.f, rintf(w.w * g))));
  ((ushort4*)qw)[v] = o;
}

// ---------- fast GELU (tanh form, branch-free) ----------
__device__ __forceinline__ float gelu_fast(float x) {
  float x2 = x * x;
  float u = x * fmaf(x2, 0.0356774081f, 0.7978845608f);
  float e = exp2f(u * 2.8853900818f);
  float r = __builtin_amdgcn_rcpf(e + 1.0f);
  return x - x * r;
}

#define SB0() __builtin_amdgcn_sched_barrier(0)
#define BAR() __builtin_amdgcn_s_barrier()
#define VMW(NN) asm volatile("s_waitcnt vmcnt(%0)" ::"n"(NN) : "memory")

// R5 epilogue (all GEMMs): operands SWAPPED -- mfma(b, a, acc) -> lane
// holds 4 CONSECUTIVE columns -> float4/ushort4 stores.
template <bool OUT_F32>
__device__ __forceinline__ void store4(void* Cv, int N, int row, int col0,
                                       const f32x4& av, const float4& bv) {
  float g0 = gelu_fast(av[0] + bv.x);
  float g1 = gelu_fast(av[1] + bv.y);
  float g2 = gelu_fast(av[2] + bv.z);
  float g3 = gelu_fast(av[3] + bv.w);
  if (OUT_F32) {
    float4 o = {g0, g1, g2, g3};
    *(float4*)&(((float*)Cv)[(size_t)row * N + col0]) = o;
  } else {
    ushort4 o;
    o.x = f2bf(g0); o.y = f2bf(g1); o.z = f2bf(g2); o.w = f2bf(g3);
    *(ushort4*)&(((ushort*)Cv)[(size_t)row * N + col0]) = o;
  }
}

// =====================================================================
// Triple-buffered 1-barrier-per-tile GEMM: BM=256, 8 waves (2M x 4N),
// BK=64, BN in {64,128}. R7 wall-stripped. Verified ~792 TF on L0.
// Do not touch.
// =====================================================================
template <int BN, bool OUT_F32>
__global__ __launch_bounds__(512, 2)
void gemm_pipe3(const ushort* __restrict__ A, const ushort* __restrict__ Bw,
                const float* __restrict__ bias, void* __restrict__ Cv,
                int M, int N, int K) {
  constexpr int BM = 256;
  constexpr int WN = BN / 4;             // 16 or 32
  constexpr int FM = 8;
  constexpr int FN = WN / 16;            // 1 or 2
  constexpr int HM = 4;
  constexpr int HN = 1;
  constexpr int SA = 4;
  constexpr int SB = BN / 64;
  constexpr int L = SA + SB;
  constexpr int TILE_USH = (BM + BN) * 64;

  __shared__ ushort lds[3 * TILE_USH];

  const int t = threadIdx.x;
  const int lane = t & 63, wid = t >> 6;
  const int wr = wid >> 2, wc = wid & 3;
  const int l15 = lane & 15, lhi = lane >> 4;

  const int gx = gridDim.x;
  const int nwg = gx * gridDim.y;
  int lin = blockIdx.y * gx + blockIdx.x;
  lin = (lin & 7) * (nwg >> 3) + (lin >> 3);  // XCD chunked (nwg % 8 == 0)
  const int bm0 = (lin / gx) * BM, bn0 = (lin % gx) * BN;

  const int NT = K >> 6;

  const int srow = t >> 3;
  const int scol = ((t & 7) ^ ((t >> 3) & 7)) * 8;

  auto stage = [&](int tile, int buf) {
    ushort* tb = &lds[buf * TILE_USH];
    const int kt = tile * 64;
#pragma unroll
    for (int c = 0; c < SA; ++c) {
      const int lr = c * 64 + srow;
      gload_lds16(A + (size_t)(bm0 + lr) * K + kt + scol,
                  &tb[lr * 64 + (t & 7) * 8]);
    }
#pragma unroll
    for (int c = 0; c < SB; ++c) {
      const int lr = c * 64 + srow;
      gload_lds16(Bw + (size_t)(bn0 + lr) * K + kt + scol,
                  &tb[BM * 64 + lr * 64 + (t & 7) * 8]);
    }
  };

  bf16x8 a[HM][2], b[HN][2];
  f32x4 acc[FM][FN] = {};

  auto loadA = [&](const ushort* tb, int mh) {
#pragma unroll
    for (int mi = 0; mi < HM; ++mi) {
      const int row = wr * 128 + (mh * HM + mi) * 16 + l15;
#pragma unroll
      for (int kh = 0; kh < 2; ++kh)
        a[mi][kh] =
            *(const bf16x8*)&tb[row * 64 + ((kh * 4 + lhi) ^ (l15 & 7)) * 8];
    }
  };
  auto loadB = [&](const ushort* tb, int nh) {
#pragma unroll
    for (int ni = 0; ni < HN; ++ni) {
      const int row = wc * WN + (nh * HN + ni) * 16 + l15;
#pragma unroll
      for (int kh = 0; kh < 2; ++kh)
        b[ni][kh] = *(const bf16x8*)&tb[BM * 64 + row * 64 +
                                        ((kh * 4 + lhi) ^ (l15 & 7)) * 8];
    }
  };

#define MFMA_(MH, NH)                                                        \
  {                                                                          \
    _Pragma("unroll") for (int kh = 0; kh < 2; ++kh)                         \
    _Pragma("unroll") for (int mi = 0; mi < HM; ++mi)                        \
    _Pragma("unroll") for (int ni = 0; ni < HN; ++ni)                        \
      acc[(MH) * HM + mi][(NH) * HN + ni] =                                  \
          __builtin_amdgcn_mfma_f32_16x16x32_bf16(                           \
              b[ni][kh], a[mi][kh], acc[(MH) * HM + mi][(NH) * HN + ni],     \
              0, 0, 0);                                                      \
  }

  stage(0, 0);
  stage(1, 1);
  VMW(L);
  BAR();

  int buf = 0, sbuf = 2;
  for (int tt = 0; tt < NT; ++tt) {
    const bool more = (tt + 2 < NT);
    if (more) stage(tt + 2, sbuf);
    const ushort* tb = &lds[buf * TILE_USH];
    if constexpr (FN == 2) {
      loadA(tb, 0); loadB(tb, 0);
      MFMA_(0, 0);
      loadB(tb, 1);
      MFMA_(0, 1);
      loadA(tb, 1);
      MFMA_(1, 1);
      loadB(tb, 0);
      MFMA_(1, 0);
    } else {
      loadA(tb, 0); loadB(tb, 0);
      MFMA_(0, 0);
      loadA(tb, 1);
      MFMA_(1, 0);
    }
    if (more) { VMW(L); } else { VMW(0); }
    BAR();
    buf = (buf == 2) ? 0 : buf + 1;
    sbuf = (sbuf == 2) ? 0 : sbuf + 1;
  }
#undef MFMA_

#pragma unroll
  for (int m = 0; m < FM; ++m) {
    const int row = bm0 + wr * 128 + m * 16 + l15;
#pragma unroll
    for (int n = 0; n < FN; ++n) {
      const int col0 = bn0 + wc * WN + n * 16 + lhi * 4;
      const float4 bv = *(const float4*)&bias[col0];
      store4<OUT_F32>(Cv, N, row, col0, acc[m][n], bv);
    }
  }
}

// =====================================================================
// R6/R7 gemm_8p2: deep-pipelined 256^2 GEMM. R10-verified ~43 us on L6.
// Do not touch.
// =====================================================================
template <bool OUT_F32>
__global__ __launch_bounds__(512, 2)
void gemm_8p2(const ushort* __restrict__ A, const ushort* __restrict__ Bw,
              const float* __restrict__ bias, void* __restrict__ Cv,
              int M, int N, int K) {
  constexpr int BM = 256;
  constexpr int BN = 256;
  constexpr int TILE_USH = (BM + BN) * 64;

  __shared__ ushort lds[2 * TILE_USH];

  const int t = threadIdx.x;
  const int lane = t & 63, wid = t >> 6;
  const int wr = wid >> 2, wc = wid & 3;
  const int l15 = lane & 15, lhi = lane >> 4;

  const int gx = gridDim.x;
  const int nwg = gx * gridDim.y;
  int lin = blockIdx.y * gx + blockIdx.x;
  lin = (lin & 7) * (nwg >> 3) + (lin >> 3);  // nwg=256, %8==0
  const int bm0 = (lin / gx) * BM, bn0 = (lin % gx) * BN;

  const int NT = K >> 6;

  const int srow = t >> 3;
  const int scol = ((t & 7) ^ ((t >> 3) & 7)) * 8;

  auto stageA = [&](ushort* tb, int kt, int h) {
#pragma unroll
    for (int c = 0; c < 2; ++c) {
      const int lr = h * 128 + c * 64 + srow;
      gload_lds16(A + (size_t)(bm0 + lr) * K + kt * 64 + scol,
                  &tb[lr * 64 + (t & 7) * 8]);
    }
  };
  auto stageB = [&](ushort* tb, int kt, int h) {
#pragma unroll
    for (int c = 0; c < 2; ++c) {
      const int lr = h * 128 + c * 64 + srow;
      gload_lds16(Bw + (size_t)(bn0 + lr) * K + kt * 64 + scol,
                  &tb[BM * 64 + lr * 64 + (t & 7) * 8]);
    }
  };

  bf16x8 a[2][4][2];   // [mh][mi][kh]
  bf16x8 b[2][2][2];   // [nh][ni][kh]
  f32x4 acc[8][4] = {};

  auto loadA = [&](const ushort* tb, int mh) {
#pragma unroll
    for (int mi = 0; mi < 4; ++mi) {
      const int row = wr * 128 + mh * 64 + mi * 16 + l15;
#pragma unroll
      for (int kh = 0; kh < 2; ++kh)
        a[mh][mi][kh] =
            *(const bf16x8*)&tb[row * 64 + ((kh * 4 + lhi) ^ (l15 & 7)) * 8];
    }
  };
  auto loadB = [&](const ushort* tb, int nh) {
#pragma unroll
    for (int ni = 0; ni < 2; ++ni) {
      const int row = wc * 64 + nh * 32 + ni * 16 + l15;
#pragma unroll
      for (int kh = 0; kh < 2; ++kh)
        b[nh][ni][kh] = *(const bf16x8*)&tb[BM * 64 + row * 64 +
                                            ((kh * 4 + lhi) ^ (l15 & 7)) * 8];
    }
  };

#define MFMA_(MH, NH)                                                        \
  {                                                                          \
    __builtin_amdgcn_s_setprio(1);                                           \
    _Pragma("unroll") for (int kh = 0; kh < 2; ++kh)                         \
    _Pragma("unroll") for (int mi = 0; mi < 4; ++mi)                         \
    _Pragma("unroll") for (int ni = 0; ni < 2; ++ni)                         \
      acc[(MH) * 4 + mi][(NH) * 2 + ni] =                                    \
          __builtin_amdgcn_mfma_f32_16x16x32_bf16(                           \
              b[(NH)][ni][kh], a[(MH)][mi][kh],                              \
              acc[(MH) * 4 + mi][(NH) * 2 + ni], 0, 0, 0);                   \
    __builtin_amdgcn_s_setprio(0);                                           \
  }

  {
    ushort* b0 = &lds[0];
    ushort* b1 = &lds[TILE_USH];
    stageA(b0, 0, 0); stageA(b0, 0, 1);
    stageB(b0, 0, 0); stageB(b0, 0, 1);
    stageA(b1, 1, 0); stageA(b1, 1, 1);
    VMW(4);
    BAR();
  }

  for (int J = 0; J < NT; ++J) {
    const ushort* tb = &lds[(J & 1) * TILE_USH];
    ushort* cb = &lds[(J & 1) * TILE_USH];
    ushort* sb = &lds[((J + 1) & 1) * TILE_USH];
    const bool s1 = (J + 1) < NT;
    const bool s2 = (J + 2) < NT;

    loadA(tb, 0);
    loadB(tb, 0);
    if (s1) stageB(sb, J + 1, 0);
    MFMA_(0, 0);
    loadA(tb, 1);
    loadB(tb, 1);
    if (s1) stageB(sb, J + 1, 1);
    MFMA_(1, 1);
    SB0();   // wall: keep all tb reads + their MFMAs above BAR(a)
    BAR();   // (a) tb A-region now globally dead
    if (s2) { stageA(cb, J + 2, 0); stageA(cb, J + 2, 1); }
    MFMA_(0, 1);
    MFMA_(1, 0);
    if (s2) { VMW(4); } else { VMW(0); }
    BAR();   // (b) publish staged halves
  }
#undef MFMA_

#pragma unroll
  for (int m = 0; m < 8; ++m) {
    const int row = bm0 + wr * 128 + m * 16 + l15;
#pragma unroll
    for (int n = 0; n < 4; ++n) {
      const int col0 = bn0 + wc * 64 + n * 16 + lhi * 4;
      const float4 bv = *(const float4*)&bias[col0];
      store4<OUT_F32>(Cv, N, row, col0, acc[m][n], bv);
    }
  }
}

// =====================================================================
// R13: fused L2+L3. Block = 32 M-rows x full N=256; 4 waves (2x2).
// Stage 1 == proven bt<32,256> geometry (K=512, A+W2 staged, bias2+gelu)
// but epilogue lands in LDS X[32][256] bf16 instead of global. Stage 2
// (K=256): A-fragments read straight from X, W3 staged in the same Bs
// buffer; bias3+gelu -> global bf16.
// X is XOR-swizzled: idx_ush = col ^ ((row&7)<<3). Writes are 4-ush
// units (4-aligned; XOR toggles bits>=3 -> unit stays intact), reads are
// 8-ush units (8-aligned; bijective per row). Write-set == read-set per
// row (8 lanes x {n,lhi,wc} partition == 8 lanes x {kt,kk,lhi}).
// No global_load_lds touches X (rule 21 safe; ds_write/ds_read both
// swizzled). Cross-block safety: reads bufA, writes bufB (in-place
// would race: block b's write rows 16b..16b+15 of A belong to block
// b/2's read set).
// =====================================================================
__global__ __launch_bounds__(256, 3)
void gemm_l2l3(const ushort* __restrict__ A, const ushort* __restrict__ W2,
               const float* __restrict__ b2, const ushort* __restrict__ W3,
               const float* __restrict__ b3, ushort* __restrict__ C) {
  __shared__ ushort As[32 * 64];    // 4 KB
  __shared__ ushort Bs[256 * 64];   // 32 KB (shared by both stages)
  __shared__ ushort X[32 * 256];    // 16 KB intermediate (gelu(L2), bf16)
  const int t = threadIdx.x;
  const int lane = t & 63, wid = t >> 6;
  const int wr = wid >> 1, wc = wid & 1;
  const int l15 = lane & 15, lhi = lane >> 4;
  const int bm0 = blockIdx.x * 32;
  const int arow = wr * 16 + l15;       // this lane's output/X row
  const int sw = (arow & 7) << 3;       // X col swizzle (ushort units)

  f32x4 acc[8] = {};

  // ---- stage 1: L2 = A(Mx512) @ W2^T, bias2+gelu -> X ----
  for (int kt = 0; kt < 512; kt += 64) {
    {
      int r = t >> 3, c8 = t & 7;
      gload_lds16(A + (size_t)(bm0 + r) * 512 + kt + c8 * 8, &As[t * 8]);
    }
#pragma unroll
    for (int i = 0; i < 8; ++i) {
      int c = i * 256 + t;
      int r = c >> 3, c8 = c & 7;
      gload_lds16(W2 + (size_t)r * 512 + kt + c8 * 8, &Bs[c * 8]);
    }
    asm volatile("s_waitcnt vmcnt(0)" ::: "memory");
    __syncthreads();
#pragma unroll
    for (int kk = 0; kk < 64; kk += 32) {
      bf16x8 af = *(const bf16x8*)&As[arow * 64 + kk + lhi * 8];
#pragma unroll
      for (int n = 0; n < 8; ++n) {
        bf16x8 bfr =
            *(const bf16x8*)&Bs[(wc * 128 + n * 16 + l15) * 64 + kk + lhi * 8];
        acc[n] = __builtin_amdgcn_mfma_f32_16x16x32_bf16(bfr, af, acc[n], 0, 0, 0);
      }
    }
    __syncthreads();
  }

  // epilogue 1 -> X (swizzled), re-zero acc for stage 2
#pragma unroll
  for (int n = 0; n < 8; ++n) {
    const int col0 = wc * 128 + n * 16 + lhi * 4;
    const float4 bv = *(const float4*)&b2[col0];
    ushort4 o;
    o.x = f2bf(gelu_fast(acc[n][0] + bv.x));
    o.y = f2bf(gelu_fast(acc[n][1] + bv.y));
    o.z = f2bf(gelu_fast(acc[n][2] + bv.z));
    o.w = f2bf(gelu_fast(acc[n][3] + bv.w));
    *(ushort4*)&X[arow * 256 + (col0 ^ sw)] = o;
    acc[n][0] = 0.f; acc[n][1] = 0.f; acc[n][2] = 0.f; acc[n][3] = 0.f;
  }
  __syncthreads();  // X complete (full drain incl. ds_write)

  // ---- stage 2: L3 = gelu(L2) @ W3^T, A from X, bias3+gelu -> C ----
  for (int kt = 0; kt < 256; kt += 64) {
#pragma unroll
    for (int i = 0; i < 8; ++i) {
      int c = i * 256 + t;
      int r = c >> 3, c8 = c & 7;
      gload_lds16(W3 + (size_t)r * 256 + kt + c8 * 8, &Bs[c * 8]);
    }
    asm volatile("s_waitcnt vmcnt(0)" ::: "memory");
    __syncthreads();
#pragma unroll
    for (int kk = 0; kk < 64; kk += 32) {
      bf16x8 af = *(const bf16x8*)&X[arow * 256 + ((kt + kk + lhi * 8) ^ sw)];
#pragma unroll
      for (int n = 0; n < 8; ++n) {
        bf16x8 bfr =
            *(const bf16x8*)&Bs[(wc * 128 + n * 16 + l15) * 64 + kk + lhi * 8];
        acc[n] = __builtin_amdgcn_mfma_f32_16x16x32_bf16(bfr, af, acc[n], 0, 0, 0);
      }
    }
    __syncthreads();
  }

#pragma unroll
  for (int n = 0; n < 8; ++n) {
    const int col0 = wc * 128 + n * 16 + lhi * 4;
    const float4 bv = *(const float4*)&b3[col0];
    store4<false>(C, 256, bm0 + arow, col0, acc[n], bv);
  }
}

// ---------- 2-phase GEMM for small layers (R2 structure; R5 epilogue) ----------
template <int BM, int BN, bool OUT_F32>
__global__ __launch_bounds__(256, 4)
void gemm_bt_bias_gelu(const ushort* __restrict__ A, const ushort* __restrict__ Bw,
                       const float* __restrict__ bias, void* __restrict__ Cv,
                       int M, int N, int K) {
  constexpr int WTM = BM / 32;
  constexpr int WTN = BN / 32;
  __shared__ ushort As[BM * 64];
  __shared__ ushort Bs[BN * 64];
  const int t = threadIdx.x;
  const int lane = t & 63, wid = t >> 6;
  const int wr = wid >> 1, wc = wid & 1;
  const int l15 = lane & 15, lhi = lane >> 4;

  const int gx = gridDim.x;
  const int nwg = gx * gridDim.y;
  int lin = blockIdx.y * gx + blockIdx.x;
  if ((nwg & 7) == 0) lin = (lin & 7) * (nwg >> 3) + (lin >> 3);
  const int bm0 = (lin / gx) * BM, bn0 = (lin % gx) * BN;

  const ushort* Abase = A + (size_t)bm0 * K;
  const ushort* Bbase = Bw + (size_t)bn0 * K;

  f32x4 acc[WTM][WTN] = {};

  for (int kt = 0; kt < K; kt += 64) {
#pragma unroll
    for (int i = 0; i < BM / 32; ++i) {
      int c = i * 256 + t;
      int r = c >> 3, c8 = c & 7;
      gload_lds16(Abase + (size_t)r * K + kt + c8 * 8, &As[c * 8]);
    }
#pragma unroll
    for (int i = 0; i < BN / 32; ++i) {
      int c = i * 256 + t;
      int r = c >> 3, c8 = c & 7;
      gload_lds16(Bbase + (size_t)r * K + kt + c8 * 8, &Bs[c * 8]);
    }
    asm volatile("s_waitcnt vmcnt(0)" ::: "memory");
    __syncthreads();
#pragma unroll
    for (int kk = 0; kk < 64; kk += 32) {
      bf16x8 af[WTM], bfr[WTN];
#pragma unroll
      for (int m = 0; m < WTM; ++m)
        af[m] = *(const bf16x8*)&As[(wr * (BM / 2) + m * 16 + l15) * 64 + kk + lhi * 8];
#pragma unroll
      for (int n = 0; n < WTN; ++n)
        bfr[n] = *(const bf16x8*)&Bs[(wc * (BN / 2) + n * 16 + l15) * 64 + kk + lhi * 8];
#pragma unroll
      for (int m = 0; m < WTM; ++m)
#pragma unroll
        for (int n = 0; n < WTN; ++n)
          acc[m][n] = __builtin_amdgcn_mfma_f32_16x16x32_bf16(bfr[n], af[m], acc[m][n], 0, 0, 0);
    }
    __syncthreads();
  }

#pragma unroll
  for (int m = 0; m < WTM; ++m) {
    const int row = bm0 + wr * (BM / 2) + m * 16 + l15;
#pragma unroll
    for (int n = 0; n < WTN; ++n) {
      const int col0 = bn0 + wc * (BN / 2) + n * 16 + lhi * 4;
      const float4 bv = *(const float4*)&bias[col0];
      store4<OUT_F32>(Cv, N, row, col0, acc[m][n], bv);
    }
  }
}

extern "C" void kernel_launch(void* const* d_in, const int* in_sizes, int n_in,
                              void* d_out, int out_size, void* d_ws, size_t ws_size,
                              hipStream_t stream) {
  const float* z   = (const float*)d_in[0];
  const float* att = (const float*)d_in[1];
  const float* Wptr[7] = {(const float*)d_in[2],  (const float*)d_in[4],
                          (const float*)d_in[6],  (const float*)d_in[8],
                          (const float*)d_in[10], (const float*)d_in[12],
                          (const float*)d_in[14]};
  const float* bptr[7] = {(const float*)d_in[3],  (const float*)d_in[5],
                          (const float*)d_in[7],  (const float*)d_in[9],
                          (const float*)d_in[11], (const float*)d_in[13],
                          (const float*)d_in[15]};
  const int Ns[7] = {1024, 512, 256, 256, 512, 1024, 2048};
  const int Ks[7] = {2048, 1024, 512, 256, 256, 512, 1024};
  const int M = 8192;

  char* ws = (char*)d_ws;
  ushort* bufA = (ushort*)ws;
  ushort* bufB = (ushort*)(ws + 33554432);
  ushort* qw   = (ushort*)(ws + 33554432 + 16777216);
  float* partials = (float*)(ws + 33554432 + 16777216 + 11141120);

  WDesc wd;
  int cum = 0;
  size_t qoff[7]; size_t qc = 0;
  for (int l = 0; l < 7; ++l) {
    wd.W[l] = Wptr[l];
    int nv = Ns[l] * Ks[l] / 4;
    wd.nvec[l] = nv;
    wd.vcum[l] = cum;
    cum += nv;
    qoff[l] = qc;
    qc += (size_t)Ns[l] * Ks[l];
  }
  wd.vcum[7] = cum;

  const int qblks = (cum + 255) / 256;
  absmean_concat<<<448 + 16384, 256, 0, stream>>>(wd, partials, z, att, bufA);
  quant_final<<<qblks, 256, 0, stream>>>(wd, partials, qw);

  ushort* inb = bufA; ushort* outb = bufB;
  // L0: 8192x1024, K=2048 -> pipe3 <BN=128>, grid (8,32)=256
  gemm_pipe3<128, false><<<dim3(Ns[0] / 128, M / 256), dim3(512), 0, stream>>>(
      inb, qw + qoff[0], bptr[0], outb, M, Ns[0], Ks[0]);
  { ushort* tmp = inb; inb = outb; outb = tmp; }
  // L1: 8192x512, K=1024 -> pipe3 <BN=64>, grid (8,32)=256
  gemm_pipe3<64, false><<<dim3(Ns[1] / 64, M / 256), dim3(512), 0, stream>>>(
      inb, qw + qoff[1], bptr[1], outb, M, Ns[1], Ks[1]);
  { ushort* tmp = inb; inb = outb; outb = tmp; }
  // L2+L3 fused (R13): reads inb, writes outb (L3 output, gelu'd bf16).
  gemm_l2l3<<<M / 32, 256, 0, stream>>>(
      inb, qw + qoff[2], bptr[2], qw + qoff[3], bptr[3], outb);
  { ushort* tmp = inb; inb = outb; outb = tmp; }
  // L4: 8192x512, K=256 -> pipe3 <BN=64>, grid (8,32)=256
  gemm_pipe3<64, false><<<dim3(Ns[4] / 64, M / 256), dim3(512), 0, stream>>>(
      inb, qw + qoff[4], bptr[4], outb, M, Ns[4], Ks[4]);
  { ushort* tmp = inb; inb = outb; outb = tmp; }
  // L5: 8192x1024, K=512 -> pipe3 <BN=128>, grid (8,32)
  gemm_pipe3<128, false><<<dim3(Ns[5] / 128, M / 256), dim3(512), 0, stream>>>(
      inb, qw + qoff[5], bptr[5], outb, M, Ns[5], Ks[5]);
  { ushort* tmp = inb; inb = outb; outb = tmp; }
  // L6: 8192x2048, K=1024 -> gemm_8p2 (R10-verified), fp32 out.
  gemm_8p2<true><<<dim3(Ns[6] / 256, M / 256), dim3(512), 0, stream>>>(
      inb, qw + qoff[6], bptr[6], d_out, M, Ns[6], Ks[6]);
}